// Round 1
// baseline (497.519 us; speedup 1.0000x reference)
//
#include <hip/hip_runtime.h>
#include <math.h>

// Problem constants (hard-coded per reference)
#define B_  8192
#define T_  204
#define I_  5
#define H_  24
#define L_  10
#define O_  612

#define EPB 8                 // elements (batch rows) per block
#define TPE 24                // threads per element (1 hidden unit each)
#define BLK (EPB * TPE)       // 192 threads = 3 waves

__device__ __forceinline__ float fast_rcp(float x) {
    return __builtin_amdgcn_rcpf(x);
}
__device__ __forceinline__ float sigm(float x) {
    // 1/(1+e^-x); e^-x may overflow to +inf for very negative x -> rcp(inf)=0 (correct)
    return fast_rcp(1.0f + __expf(-x));
}
__device__ __forceinline__ float tanh_fast(float x) {
    float ax = fabsf(x);
    float e  = __expf(-2.0f * ax);          // in (0,1], underflows to 0 for big ax
    float r  = (1.0f - e) * fast_rcp(1.0f + e);
    return copysignf(r, x);
}

__global__ __launch_bounds__(BLK, 3)
void lstm_fused_kernel(const float* __restrict__ x,
                       const float* __restrict__ W_ih,
                       const float* __restrict__ W_hh,
                       const float* __restrict__ b_ih,
                       const float* __restrict__ b_hh,
                       const float* __restrict__ fc0_w,
                       const float* __restrict__ fc0_b,
                       const float* __restrict__ out_w,
                       const float* __restrict__ out_b,
                       float* __restrict__ out)
{
    __shared__ __align__(16) float h_buf[2][EPB][H_];   // 1536 B, double-buffered h
    __shared__ __align__(16) float x_buf[2][EPB][8];    // 512 B, padded to 8 for alignment
    __shared__ __align__(16) float red[EPB][H_][L_];    // 7680 B, fc0 partial reduction
    __shared__ __align__(16) float act[EPB][L_];        // 320 B, relu(fc0) activations

    const int tid = threadIdx.x;
    const int e   = tid / TPE;          // element within block
    const int j   = tid - e * TPE;      // hidden unit owned by this thread
    const int b   = blockIdx.x * EPB + e;

    // ---- Preload this thread's weight rows into registers ----
    // Gate rows (torch order i,f,g,o): j, 24+j, 48+j, 72+j
    float whh[4][H_];
    float wih[4][I_];
    float bias[4];
    #pragma unroll
    for (int g = 0; g < 4; ++g) {
        const int row = g * H_ + j;
        const float4* wrow = reinterpret_cast<const float4*>(W_hh + row * H_); // 96B-aligned
        #pragma unroll
        for (int k4 = 0; k4 < H_ / 4; ++k4) {
            float4 w = wrow[k4];
            whh[g][k4*4+0] = w.x; whh[g][k4*4+1] = w.y;
            whh[g][k4*4+2] = w.z; whh[g][k4*4+3] = w.w;
        }
        #pragma unroll
        for (int i = 0; i < I_; ++i) wih[g][i] = W_ih[row * I_ + i];
        bias[g] = b_ih[row] + b_hh[row];
    }

    float facc[L_];
    #pragma unroll
    for (int l = 0; l < L_; ++l) facc[l] = 0.0f;

    // ---- init state ----
    const float* xp = x + (size_t)b * (T_ * I_);
    h_buf[0][e][j] = 0.0f;
    if (j < I_) x_buf[0][e][j] = xp[j];
    float c = 0.0f;

    // ---- time loop ----
    for (int t = 0; t < T_; ++t) {
        __syncthreads();   // publishes h_buf/x_buf[t&1] written last iteration
        const int cur = t & 1, nxt = cur ^ 1;

        float a0 = bias[0], a1 = bias[1], a2 = bias[2], a3 = bias[3];

        // input projection (x broadcast from LDS)
        #pragma unroll
        for (int i = 0; i < I_; ++i) {
            const float xv = x_buf[cur][e][i];
            a0 = fmaf(wih[0][i], xv, a0);
            a1 = fmaf(wih[1][i], xv, a1);
            a2 = fmaf(wih[2][i], xv, a2);
            a3 = fmaf(wih[3][i], xv, a3);
        }

        // recurrent projection: h broadcast reads, register weights
        const float4* h4p = reinterpret_cast<const float4*>(&h_buf[cur][e][0]);
        #pragma unroll
        for (int k4 = 0; k4 < H_ / 4; ++k4) {
            const float4 hv = h4p[k4];
            #pragma unroll
            for (int u = 0; u < 4; ++u) {
                const float hk = (&hv.x)[u];
                const int k = k4 * 4 + u;
                a0 = fmaf(whh[0][k], hk, a0);
                a1 = fmaf(whh[1][k], hk, a1);
                a2 = fmaf(whh[2][k], hk, a2);
                a3 = fmaf(whh[3][k], hk, a3);
            }
        }

        const float ig = sigm(a0);
        const float fg = sigm(a1);
        const float gg = tanh_fast(a2);
        const float og = sigm(a3);
        c = fmaf(fg, c, ig * gg);
        const float h = og * tanh_fast(c);

        h_buf[nxt][e][j] = h;
        if (j < I_ && (t + 1) < T_) x_buf[nxt][e][j] = xp[(t + 1) * I_ + j];

        // fc0 partial accumulation: fc0_w[l][t*24 + j]
        const int fidx = t * H_ + j;
        #pragma unroll
        for (int l = 0; l < L_; ++l)
            facc[l] = fmaf(fc0_w[l * (T_ * H_) + fidx], h, facc[l]);
    }

    // ---- reduce fc0 partials across the 24 threads of each element ----
    #pragma unroll
    for (int l = 0; l < L_; ++l) red[e][j][l] = facc[l];
    __syncthreads();

    if (tid < EPB * L_) {
        const int ee = tid / L_, l = tid - ee * L_;
        float s = fc0_b[l];
        #pragma unroll
        for (int k = 0; k < H_; ++k) s += red[ee][k][l];
        act[ee][l] = fmaxf(s, 0.0f);
    }
    __syncthreads();

    // ---- output layer: [EPB,10] x [612,10]^T ----
    for (int idx = tid; idx < EPB * O_; idx += BLK) {
        const int ee = idx / O_, o = idx - ee * O_;
        float s = out_b[o];
        #pragma unroll
        for (int l = 0; l < L_; ++l)
            s = fmaf(act[ee][l], out_w[o * L_ + l], s);
        out[(size_t)(blockIdx.x * EPB + ee) * O_ + o] = s;
    }
}

extern "C" void kernel_launch(void* const* d_in, const int* in_sizes, int n_in,
                              void* d_out, int out_size, void* d_ws, size_t ws_size,
                              hipStream_t stream)
{
    const float* x     = (const float*)d_in[0];
    const float* W_ih  = (const float*)d_in[1];
    const float* W_hh  = (const float*)d_in[2];
    const float* b_ih  = (const float*)d_in[3];
    const float* b_hh  = (const float*)d_in[4];
    const float* fc0_w = (const float*)d_in[5];
    const float* fc0_b = (const float*)d_in[6];
    const float* out_w = (const float*)d_in[7];
    const float* out_b = (const float*)d_in[8];
    float* out = (float*)d_out;

    dim3 grid(B_ / EPB);   // 1024 blocks, 4 per CU
    dim3 block(BLK);       // 192 threads
    lstm_fused_kernel<<<grid, block, 0, stream>>>(
        x, W_ih, W_hh, b_ih, b_hh, fc0_w, fc0_b, out_w, out_b, out);
}

// Round 2
// 495.041 us; speedup vs baseline: 1.0050x; 1.0050x over previous
//
#include <hip/hip_runtime.h>
#include <math.h>

// Problem constants (hard-coded per reference)
#define B_  8192
#define T_  204
#define I_  5
#define H_  24
#define L_  10
#define O_  612

#define EPB 8                 // elements (batch rows) per block
#define TPE 24                // threads per element (1 hidden unit each)
#define BLK (EPB * TPE)       // 192 threads = 3 waves

__device__ __forceinline__ float fast_rcp(float x) {
    return __builtin_amdgcn_rcpf(x);
}
__device__ __forceinline__ float sigm(float x) {
    // 1/(1+e^-x); e^-x may overflow to +inf for very negative x -> rcp(inf)=0 (correct)
    return fast_rcp(1.0f + __expf(-x));
}
__device__ __forceinline__ float tanh_fast(float x) {
    float ax = fabsf(x);
    float e  = __expf(-2.0f * ax);          // in (0,1], underflows to 0 for big ax
    float r  = (1.0f - e) * fast_rcp(1.0f + e);
    return copysignf(r, x);
}

__global__ __launch_bounds__(BLK, 3)
void lstm_fused_kernel(const float* __restrict__ x,
                       const float* __restrict__ W_ih,
                       const float* __restrict__ W_hh,
                       const float* __restrict__ b_ih,
                       const float* __restrict__ b_hh,
                       const float* __restrict__ fc0_w,
                       const float* __restrict__ fc0_b,
                       const float* __restrict__ out_w,
                       const float* __restrict__ out_b,
                       float* __restrict__ out)
{
    __shared__ __align__(16) float h_buf[2][EPB][H_];   // 1536 B, double-buffered h
    __shared__ __align__(16) float x_buf[2][EPB][8];    // 512 B, padded to 8 for alignment
    __shared__ __align__(16) float red[EPB][H_][L_];    // 7680 B, fc0 partial reduction
    __shared__ __align__(16) float act[EPB][L_];        // 320 B, relu(fc0) activations

    const int tid = threadIdx.x;
    const int e   = tid / TPE;          // element within block
    const int j   = tid - e * TPE;      // hidden unit owned by this thread
    const int b   = blockIdx.x * EPB + e;

    // ---- Preload this thread's weight rows into registers ----
    // Gate rows (torch order i,f,g,o): j, 24+j, 48+j, 72+j
    float whh[4][H_];
    float wih[4][I_];
    float bias[4];
    #pragma unroll
    for (int g = 0; g < 4; ++g) {
        const int row = g * H_ + j;
        const float4* wrow = reinterpret_cast<const float4*>(W_hh + row * H_); // 96B-aligned
        #pragma unroll
        for (int k4 = 0; k4 < H_ / 4; ++k4) {
            float4 w = wrow[k4];
            whh[g][k4*4+0] = w.x; whh[g][k4*4+1] = w.y;
            whh[g][k4*4+2] = w.z; whh[g][k4*4+3] = w.w;
        }
        #pragma unroll
        for (int i = 0; i < I_; ++i) wih[g][i] = W_ih[row * I_ + i];
        bias[g] = b_ih[row] + b_hh[row];
    }

    // ---- PIN weights into VGPRs ----
    // R1 post-mortem: without this the compiler demotes the 120-float weight
    // state to per-iteration L1 reloads (VGPR_Count=84 < 120), and the kernel
    // becomes L1-bandwidth-bound (73.7 KB/step/block -> ~390us). The empty asm
    // makes each value asm-defined so it cannot be rematerialized from memory.
    #pragma unroll
    for (int g = 0; g < 4; ++g) {
        #pragma unroll
        for (int k = 0; k < H_; ++k) asm volatile("" : "+v"(whh[g][k]));
        #pragma unroll
        for (int i = 0; i < I_; ++i) asm volatile("" : "+v"(wih[g][i]));
        asm volatile("" : "+v"(bias[g]));
    }

    float facc[L_];
    #pragma unroll
    for (int l = 0; l < L_; ++l) facc[l] = 0.0f;

    // ---- init state ----
    const float* xp = x + (size_t)b * (T_ * I_);
    h_buf[0][e][j] = 0.0f;
    if (j < I_) x_buf[0][e][j] = xp[j];
    float c = 0.0f;

    // ---- time loop ----
    for (int t = 0; t < T_; ++t) {
        __syncthreads();   // publishes h_buf/x_buf[t&1] written last iteration
        const int cur = t & 1, nxt = cur ^ 1;

        float a0 = bias[0], a1 = bias[1], a2 = bias[2], a3 = bias[3];

        // input projection (x broadcast from LDS)
        #pragma unroll
        for (int i = 0; i < I_; ++i) {
            const float xv = x_buf[cur][e][i];
            a0 = fmaf(wih[0][i], xv, a0);
            a1 = fmaf(wih[1][i], xv, a1);
            a2 = fmaf(wih[2][i], xv, a2);
            a3 = fmaf(wih[3][i], xv, a3);
        }

        // recurrent projection: h broadcast reads, register weights
        const float4* h4p = reinterpret_cast<const float4*>(&h_buf[cur][e][0]);
        #pragma unroll
        for (int k4 = 0; k4 < H_ / 4; ++k4) {
            const float4 hv = h4p[k4];
            #pragma unroll
            for (int u = 0; u < 4; ++u) {
                const float hk = (&hv.x)[u];
                const int k = k4 * 4 + u;
                a0 = fmaf(whh[0][k], hk, a0);
                a1 = fmaf(whh[1][k], hk, a1);
                a2 = fmaf(whh[2][k], hk, a2);
                a3 = fmaf(whh[3][k], hk, a3);
            }
        }

        const float ig = sigm(a0);
        const float fg = sigm(a1);
        const float gg = tanh_fast(a2);
        const float og = sigm(a3);
        c = fmaf(fg, c, ig * gg);
        const float h = og * tanh_fast(c);

        h_buf[nxt][e][j] = h;
        if (j < I_ && (t + 1) < T_) x_buf[nxt][e][j] = xp[(t + 1) * I_ + j];

        // fc0 partial accumulation: fc0_w[l][t*24 + j]
        const int fidx = t * H_ + j;
        #pragma unroll
        for (int l = 0; l < L_; ++l)
            facc[l] = fmaf(fc0_w[l * (T_ * H_) + fidx], h, facc[l]);
    }

    // ---- reduce fc0 partials across the 24 threads of each element ----
    #pragma unroll
    for (int l = 0; l < L_; ++l) red[e][j][l] = facc[l];
    __syncthreads();

    if (tid < EPB * L_) {
        const int ee = tid / L_, l = tid - ee * L_;
        float s = fc0_b[l];
        #pragma unroll
        for (int k = 0; k < H_; ++k) s += red[ee][k][l];
        act[ee][l] = fmaxf(s, 0.0f);
    }
    __syncthreads();

    // ---- output layer: [EPB,10] x [612,10]^T ----
    for (int idx = tid; idx < EPB * O_; idx += BLK) {
        const int ee = idx / O_, o = idx - ee * O_;
        float s = out_b[o];
        #pragma unroll
        for (int l = 0; l < L_; ++l)
            s = fmaf(act[ee][l], out_w[o * L_ + l], s);
        out[(size_t)(blockIdx.x * EPB + ee) * O_ + o] = s;
    }
}

extern "C" void kernel_launch(void* const* d_in, const int* in_sizes, int n_in,
                              void* d_out, int out_size, void* d_ws, size_t ws_size,
                              hipStream_t stream)
{
    const float* x     = (const float*)d_in[0];
    const float* W_ih  = (const float*)d_in[1];
    const float* W_hh  = (const float*)d_in[2];
    const float* b_ih  = (const float*)d_in[3];
    const float* b_hh  = (const float*)d_in[4];
    const float* fc0_w = (const float*)d_in[5];
    const float* fc0_b = (const float*)d_in[6];
    const float* out_w = (const float*)d_in[7];
    const float* out_b = (const float*)d_in[8];
    float* out = (float*)d_out;

    dim3 grid(B_ / EPB);   // 1024 blocks, 4 per CU
    dim3 block(BLK);       // 192 threads
    lstm_fused_kernel<<<grid, block, 0, stream>>>(
        x, W_ih, W_hh, b_ih, b_hh, fc0_w, fc0_b, out_w, out_b, out);
}

// Round 3
// 461.024 us; speedup vs baseline: 1.0792x; 1.0738x over previous
//
#include <hip/hip_runtime.h>
#include <math.h>

// Problem constants (hard-coded per reference)
#define B_  8192
#define T_  204
#define I_  5
#define H_  24
#define L_  10
#define O_  612

#define TPE 48                // threads per element: 2 per hidden unit (p=0: gates i,f; p=1: g,o)
#define EPB 4                 // elements per block
#define BLK (EPB * TPE)       // 192 threads = 3 waves

__device__ __forceinline__ float fast_rcp(float x) {
    return __builtin_amdgcn_rcpf(x);
}
__device__ __forceinline__ float sigm(float x) {
    // 1/(1+e^-x); e^-x overflows to +inf for very negative x -> rcp(inf)=0 (correct)
    return fast_rcp(1.0f + __expf(-x));
}
__device__ __forceinline__ float tanh_fast(float x) {
    float ax = fabsf(x);
    float e  = __expf(-2.0f * ax);
    float r  = (1.0f - e) * fast_rcp(1.0f + e);
    return copysignf(r, x);
}

// R2 post-mortem: 120 weight floats/thread got AGPR-spilled (VGPR_Count=84,
// identical binary with/without asm pin; VALU cycles ~3x the FMA model).
// Fix: halve footprint -> 2 threads per hidden unit, ~80 live floats/thread.
__global__ __launch_bounds__(BLK, 3)
void lstm_fused_kernel(const float* __restrict__ x,
                       const float* __restrict__ W_ih,
                       const float* __restrict__ W_hh,
                       const float* __restrict__ b_ih,
                       const float* __restrict__ b_hh,
                       const float* __restrict__ fc0_w,
                       const float* __restrict__ fc0_b,
                       const float* __restrict__ out_w,
                       const float* __restrict__ out_b,
                       float* __restrict__ out)
{
    __shared__ __align__(16) float h_buf[2][EPB][H_];       // 768 B
    __shared__ __align__(16) float x_buf[2][EPB][8];        // 256 B
    __shared__ __align__(16) float red[EPB][2][H_][L_/2];   // 3840 B fc0 partials
    __shared__ __align__(16) float act[EPB][L_];            // 160 B

    const int tid = threadIdx.x;
    const int e   = tid / TPE;            // element within block
    const int r   = tid - e * TPE;        // 0..47
    const int j   = r >> 1;               // hidden unit 0..23
    const int p   = r & 1;                // gate pair: 0 -> (i,f), 1 -> (g,o)
    const int b   = blockIdx.x * EPB + e;

    // ---- preload this thread's 2 gate rows (torch order i,f,g,o) ----
    const int rowA = (p ? 2 : 0) * H_ + j;   // i or g
    const int rowB = (p ? 3 : 1) * H_ + j;   // f or o
    float whhA[H_], whhB[H_], wihA[I_], wihB[I_];
    {
        const float4* wa = reinterpret_cast<const float4*>(W_hh + rowA * H_);
        const float4* wb = reinterpret_cast<const float4*>(W_hh + rowB * H_);
        #pragma unroll
        for (int k4 = 0; k4 < H_ / 4; ++k4) {
            float4 a = wa[k4], bb = wb[k4];
            whhA[k4*4+0]=a.x; whhA[k4*4+1]=a.y; whhA[k4*4+2]=a.z; whhA[k4*4+3]=a.w;
            whhB[k4*4+0]=bb.x; whhB[k4*4+1]=bb.y; whhB[k4*4+2]=bb.z; whhB[k4*4+3]=bb.w;
        }
        #pragma unroll
        for (int i = 0; i < I_; ++i) { wihA[i] = W_ih[rowA*I_+i]; wihB[i] = W_ih[rowB*I_+i]; }
    }
    const float biasA = b_ih[rowA] + b_hh[rowA];
    const float biasB = b_ih[rowB] + b_hh[rowB];

    // fc0 rows owned by this thread: l = p*5 .. p*5+4, column t*24+j
    const float* fw = fc0_w + (size_t)(p * (L_/2)) * (T_ * H_) + j;
    float facc[L_/2];
    #pragma unroll
    for (int l = 0; l < L_/2; ++l) facc[l] = 0.0f;

    // ---- init state ----
    const float* xp = x + (size_t)b * (T_ * I_);
    if (r < H_) h_buf[0][e][r] = 0.0f;
    if (r < I_) x_buf[0][e][r] = xp[r];
    float c = 0.0f;

    // ---- time loop ----
    for (int t = 0; t < T_; ++t) {
        __syncthreads();   // publishes h_buf/x_buf[t&1] written last iteration
        const int cur = t & 1, nxt = cur ^ 1;

        float aA = biasA, aB = biasB;

        #pragma unroll
        for (int i = 0; i < I_; ++i) {
            const float xv = x_buf[cur][e][i];
            aA = fmaf(wihA[i], xv, aA);
            aB = fmaf(wihB[i], xv, aB);
        }

        const float4* h4p = reinterpret_cast<const float4*>(&h_buf[cur][e][0]);
        #pragma unroll
        for (int k4 = 0; k4 < H_ / 4; ++k4) {
            const float4 hv = h4p[k4];
            #pragma unroll
            for (int u = 0; u < 4; ++u) {
                const float hk = (&hv.x)[u];
                const int k = k4 * 4 + u;
                aA = fmaf(whhA[k], hk, aA);
                aB = fmaf(whhB[k], hk, aB);
            }
        }

        // Uniform activation: p=0 -> gA=sigm(aA) [i], p=1 -> gA=tanh(aA)=2*sigm(2aA)-1 [g]
        // gB = sigm(aB) for both (f and o are sigmoids).
        const float sA = sigm(p ? 2.0f * aA : aA);
        const float gA = p ? 2.0f * sA - 1.0f : sA;     // i_s (p=0) or g_t (p=1)
        const float gB = sigm(aB);                      // f_s (p=0) or o_s (p=1)

        // exchange with partner lane (lane^1): each lane then holds all 4 gates
        const float oA = __shfl_xor(gA, 1, 64);
        const float oB = __shfl_xor(gB, 1, 64);
        const float i_s = p ? oA : gA;
        const float f_s = p ? oB : gB;
        const float g_t = p ? gA : oA;
        const float o_s = p ? gB : oB;

        // both lanes maintain identical c/h (no divergence, no second exchange)
        c = fmaf(f_s, c, i_s * g_t);
        const float h = o_s * tanh_fast(c);

        if (p == 0) h_buf[nxt][e][j] = h;
        if (r < I_ && (t + 1) < T_) x_buf[nxt][e][r] = xp[(t + 1) * I_ + r];

        // fc0 partial accumulation (5 rows per thread)
        const int col = t * H_;
        #pragma unroll
        for (int l = 0; l < L_/2; ++l)
            facc[l] = fmaf(fw[(size_t)l * (T_ * H_) + col], h, facc[l]);
    }

    // ---- fc0 reduction across the 24 units ----
    #pragma unroll
    for (int l = 0; l < L_/2; ++l) red[e][p][j][l] = facc[l];
    __syncthreads();

    if (tid < EPB * L_) {
        const int ee = tid / L_, l = tid - ee * L_;
        const int pp = l / (L_/2), li = l - pp * (L_/2);
        float s = fc0_b[l];
        #pragma unroll
        for (int k = 0; k < H_; ++k) s += red[ee][pp][k][li];
        act[ee][l] = fmaxf(s, 0.0f);
    }
    __syncthreads();

    // ---- output layer: [EPB,10] x [612,10]^T ----
    for (int idx = tid; idx < EPB * O_; idx += BLK) {
        const int ee = idx / O_, o = idx - ee * O_;
        float s = out_b[o];
        #pragma unroll
        for (int l = 0; l < L_; ++l)
            s = fmaf(act[ee][l], out_w[o * L_ + l], s);
        out[(size_t)(blockIdx.x * EPB + ee) * O_ + o] = s;
    }
}

extern "C" void kernel_launch(void* const* d_in, const int* in_sizes, int n_in,
                              void* d_out, int out_size, void* d_ws, size_t ws_size,
                              hipStream_t stream)
{
    const float* x     = (const float*)d_in[0];
    const float* W_ih  = (const float*)d_in[1];
    const float* W_hh  = (const float*)d_in[2];
    const float* b_ih  = (const float*)d_in[3];
    const float* b_hh  = (const float*)d_in[4];
    const float* fc0_w = (const float*)d_in[5];
    const float* fc0_b = (const float*)d_in[6];
    const float* out_w = (const float*)d_in[7];
    const float* out_b = (const float*)d_in[8];
    float* out = (float*)d_out;

    dim3 grid(B_ / EPB);   // 2048 blocks
    dim3 block(BLK);       // 192 threads
    lstm_fused_kernel<<<grid, block, 0, stream>>>(
        x, W_ih, W_hh, b_ih, b_hh, fc0_w, fc0_b, out_w, out_b, out);
}